// Round 11
// baseline (50065.585 us; speedup 1.0000x reference)
//
#include <hip/hip_runtime.h>
#include <cmath>

#define NWG 256
#define NT  512

typedef unsigned long long u64;
typedef unsigned short u16;
typedef unsigned int u32;

// ---------------- workspace layout (float offsets) ----------------
static constexpr size_t XB_   = 8192;                        // u16 [t][b][64k]
static constexpr size_t H1B_  = XB_   + 1048576;             // u16 [t][b][512k]
static constexpr size_t ENCQ_ = H1B_  + 8388608;             // u16 [b][512k][512s]
static constexpr size_t WQ0_  = ENCQ_ + 8388608;             // u32 [2d][320k][512p]
static constexpr size_t WQ1_  = WQ0_  + 327680;              // u32 [2d][768k][512p]
static constexpr size_t HF_   = WQ1_  + 786432;              // f32 [512k][64b]
static constexpr size_t CF_   = HF_   + 32768;               // f32 [512k][64b]
static constexpr size_t SCP_  = CF_   + 32768;               // f32 [32cl][2b][2hc][8sl][512s]
static constexpr size_t PROJ_ = SCP_  + 524288;              // f32 [2buf][64b][8sl]
static constexpr size_t GP_   = PROJ_ + 1024;                // u64 [32cl][8sl][2048r]
static constexpr size_t WDK_  = GP_   + 1048576;             // u64 [8sl][200k][512p]

// ---------------- LDS layout (float offsets) ----------------
// decoder (unchanged from r10):
static constexpr int SLAB_F = 0;       // u32 [2b][64u][256c] swizzled  32768
static constexpr int WSM_F  = 32768;   // f32 [2b][2hc][512s]           2048
static constexpr int ACTL_F = 34816;   // f32 [2b][200k]                400
static constexpr int RED_F  = 35216;   // f32 [1024]
static constexpr int GTS_F  = 36240;   // f32 [2b][256r]                512
static constexpr int BI_F   = 36752;   // f32 [256]
static constexpr int HCL_F  = 37008;   // f32 h[2][64] c[2][64]         256
static constexpr int CXL_F  = 37264;   // f32 [2b][2hc][64]             256
static constexpr int WPS_F  = 37520;   // f32 [64]
static constexpr int SMX_F  = 37584;   // f32 [64]
static constexpr int SMEM_F = 37648;   // 150,592 B
// encoder aliases (time-disjoint, batch-local):
static constexpr int ENH_F = 0;        // f32 h[2][256]
static constexpr int ENC2_F = 512;     // f32 c[2][256]
static constexpr int ENX_F = 1024;     // f32 xin[2][512]
static constexpr int ENG_F = 2048;     // f32 graw[2][1024]
static constexpr int ENB_F = 4096;     // f32 bias[1024]

__device__ __forceinline__ float sigm(float v) { return 1.f / (1.f + expf(-v)); }
__device__ __forceinline__ u16 f2bf(float f) {
  u32 u = __float_as_uint(f);
  u += 0x7fffu + ((u >> 16) & 1u);
  return (u16)(u >> 16);
}
__device__ __forceinline__ float bf2f(u16 h) { return __uint_as_float((u32)h << 16); }
__device__ __forceinline__ u64 pk2f(float a, float b) {
  return (u64)__float_as_uint(a) | ((u64)__float_as_uint(b) << 32);
}

__device__ __forceinline__ unsigned uld(unsigned* p) {
  return __hip_atomic_load(p, __ATOMIC_RELAXED, __HIP_MEMORY_SCOPE_AGENT);
}
__device__ __forceinline__ unsigned uadd(unsigned* p) {
  return __hip_atomic_fetch_add(p, 1u, __ATOMIC_RELAXED, __HIP_MEMORY_SCOPE_AGENT);
}
__device__ __forceinline__ float ald(const float* p) {
  return __hip_atomic_load(p, __ATOMIC_RELAXED, __HIP_MEMORY_SCOPE_AGENT);
}
__device__ __forceinline__ void ast(float* p, float v) {
  __hip_atomic_store(p, v, __ATOMIC_RELAXED, __HIP_MEMORY_SCOPE_AGENT);
}
__device__ __forceinline__ u64 a64ld(const u64* p) {
  return __hip_atomic_load(p, __ATOMIC_RELAXED, __HIP_MEMORY_SCOPE_AGENT);
}
__device__ __forceinline__ void a64st(u64* p, u64 v) {
  __hip_atomic_store(p, v, __ATOMIC_RELAXED, __HIP_MEMORY_SCOPE_AGENT);
}
__device__ __forceinline__ void acqf() { __builtin_amdgcn_fence(__ATOMIC_ACQUIRE, "agent"); }
__device__ __forceinline__ void relf() { __builtin_amdgcn_fence(__ATOMIC_RELEASE, "agent"); }

// full-grid barrier WITH fences (phase boundaries only)
__device__ __forceinline__ void fullbar(unsigned* bar, int wg) {
  __syncthreads();
  if (threadIdx.x == 0) {
    relf();
    unsigned g = uld(bar);
    if (((uadd(&bar[32 + (wg >> 3) * 32]) + 1) & 7) == 0)
      if (((uadd(&bar[1056 + (wg >> 6) * 32]) + 1) & 7) == 0)
        if (((uadd(&bar[1184]) + 1) & 3) == 0)
          uadd(bar);
    while (uld(bar) == g) __builtin_amdgcn_s_sleep(4);
    acqf();
  }
  __syncthreads();
}

// 8-WG relaxed minibar, fence-free
__device__ __forceinline__ void mbar8(unsigned* base) {
  __syncthreads();
  if (threadIdx.x == 0) {
    unsigned g = uld(base);
    if (((uadd(&base[32]) + 1) & 7) == 0) uadd(base);
    while (uld(base) == g) __builtin_amdgcn_s_sleep(1);
  }
  __syncthreads();
}

extern "C" __global__ void __launch_bounds__(NT, 1)
seq2seq_ker(const float* __restrict__ x,
            const float* __restrict__ Wih0, const float* __restrict__ Whh0,
            const float* __restrict__ bih0, const float* __restrict__ bhh0,
            const float* __restrict__ Wih1, const float* __restrict__ Whh1,
            const float* __restrict__ bih1, const float* __restrict__ bhh1,
            const float* __restrict__ Wihd, const float* __restrict__ Whhd,
            const float* __restrict__ bihd, const float* __restrict__ bhhd,
            const float* __restrict__ Wp,   const float* __restrict__ bp,
            float* out, float* ws) {
  extern __shared__ float smem[];
  unsigned* bar = (unsigned*)ws;
  const int tid = threadIdx.x;
  const int wg  = blockIdx.x;
  const int gtid = wg * NT + tid;
  const int lane = tid & 63, q = tid >> 6;

  // ---------- prologue: XB, WQ0, WQ1, WDK ----------
  for (size_t i = gtid; i < (size_t)512 * 64 * 64; i += (size_t)NWG * NT) {
    int k = (int)(i & 63), tt2 = (int)((i >> 6) & 511), bb = (int)(i >> 15);
    ((u16*)(ws + XB_))[((size_t)tt2 * 64 + bb) * 64 + k] = f2bf(x[i]);
  }
  // encoder L0 weights: [d][320 k][512 p] u32 (rows 2p,2p+1 bf16-packed)
  for (size_t idx = gtid; idx < (size_t)2 * 320 * 512; idx += (size_t)NWG * NT) {
    int p = (int)(idx & 511);
    int k = (int)((idx >> 9) % 320);
    int d = (int)((idx >> 9) / 320);
    u32 v = 0;
#pragma unroll
    for (int j = 0; j < 2; ++j) {
      int row = 2 * p + j;
      float wv = (k < 64) ? Wih0[(size_t)d * 65536 + (size_t)row * 64 + k]
                          : Whh0[(size_t)d * 262144 + (size_t)row * 256 + (k - 64)];
      v |= (u32)f2bf(wv) << (16 * j);
    }
    ((u32*)(ws + WQ0_))[idx] = v;
  }
  // encoder L1 weights: [d][768 k][512 p]
  for (size_t idx = gtid; idx < (size_t)2 * 768 * 512; idx += (size_t)NWG * NT) {
    int p = (int)(idx & 511);
    int k = (int)((idx >> 9) % 768);
    int d = (int)((idx >> 9) / 768);
    u32 v = 0;
#pragma unroll
    for (int j = 0; j < 2; ++j) {
      int row = 2 * p + j;
      float wv = (k < 512) ? Wih1[(size_t)d * 524288 + (size_t)row * 512 + k]
                           : Whh1[(size_t)d * 262144 + (size_t)row * 256 + (k - 512)];
      v |= (u32)f2bf(wv) << (16 * j);
    }
    ((u32*)(ws + WQ1_))[idx] = v;
  }
  // decoder weights, K-split chunks: WDK[sl][200 k][512 p] u64 (4 rows bf16)
  for (size_t idx = gtid; idx < (size_t)8 * 200 * 512; idx += (size_t)NWG * NT) {
    int p = (int)(idx & 511);
    int k = (int)((idx >> 9) % 200);
    int sl2 = (int)((idx >> 9) / 200);
    int a = (k < 8)   ? sl2 * 8 + k
          : (k < 72)  ? 64 + sl2 * 64 + (k - 8)
          : (k < 136) ? 576 + sl2 * 64 + (k - 72)
                      : 1088 + sl2 * 64 + (k - 136);
    u64 v = 0;
#pragma unroll
    for (int j = 0; j < 4; ++j) {
      int row = 4 * p + j;
      float wv = (a < 1088) ? Wihd[(size_t)row * 1088 + a]
                            : Whhd[(size_t)row * 512 + (a - 1088)];
      v |= (u64)f2bf(wv) << (16 * j);
    }
    ((u64*)(ws + WDK_))[idx] = v;
  }
  fullbar(bar, wg);   // XB / WQ0 / WQ1 / WDK visible

  // ---------- encoder: batch-parallel, ZERO inter-WG sync within a layer ----------
  // 64 active WGs: d = wg>>5 (direction), bp = wg&31 (batch pair), b0 = 2*bp
  {
    float* h    = smem + ENH_F;    // [2][256]
    float* c    = smem + ENC2_F;   // [2][256]
    float* xin  = smem + ENX_F;    // [2][512]
    float* graw = smem + ENG_F;    // [2][1024]
    float* bia  = smem + ENB_F;    // [1024]
    const int d = wg >> 5, b0 = (wg & 31) * 2;
    const bool act = (wg < 64);

    for (int layer = 0; layer < 2; ++layer) {
      if (act) {
        // stage bias; zero h,c
        for (int i = tid; i < 1024; i += NT)
          bia[i] = (layer == 0) ? (bih0[d * 1024 + i] + bhh0[d * 1024 + i])
                                : (bih1[d * 1024 + i] + bhh1[d * 1024 + i]);
        if (tid < 512) { h[tid] = 0.f; c[tid] = 0.f; }
        __syncthreads();

        const u32* wq = (const u32*)(ws + (layer == 0 ? WQ0_ : WQ1_))
                        + (size_t)d * (layer == 0 ? 320 : 768) * 512;
        const int KI = (layer == 0) ? 64 : 512;

        for (int t = 0; t < 512; ++t) {
          const int tt = d ? (511 - t) : t;
          // stage inputs
          if (layer == 0) {
            if (tid < 128) {
              int bb = tid >> 6, k = tid & 63;
              xin[bb * 512 + k] = bf2f(((const u16*)(ws + XB_))[((size_t)tt * 64 + b0 + bb) * 64 + k]);
            }
          } else {
            for (int i = tid; i < 1024; i += NT) {
              int bb = i >> 9, k = i & 511;
              xin[bb * 512 + k] = bf2f(((const u16*)(ws + H1B_))[((size_t)tt * 64 + b0 + bb) * 512 + k]);
            }
          }
          __syncthreads();

          float a00 = 0.f, a10 = 0.f, a01 = 0.f, a11 = 0.f;  // a[row j][batch bb]
          if (layer == 0) {
#pragma unroll 8
            for (int k = 0; k < 64; ++k) {
              u32 wv = wq[(size_t)k * 512 + tid];
              float w0 = bf2f((u16)wv), w1 = bf2f((u16)(wv >> 16));
              float x0 = xin[k], x1 = xin[512 + k];
              a00 = fmaf(w0, x0, a00); a01 = fmaf(w0, x1, a01);
              a10 = fmaf(w1, x0, a10); a11 = fmaf(w1, x1, a11);
            }
          } else {
#pragma unroll 8
            for (int k = 0; k < 512; ++k) {
              u32 wv = wq[(size_t)k * 512 + tid];
              float w0 = bf2f((u16)wv), w1 = bf2f((u16)(wv >> 16));
              float x0 = xin[k], x1 = xin[512 + k];
              a00 = fmaf(w0, x0, a00); a01 = fmaf(w0, x1, a01);
              a10 = fmaf(w1, x0, a10); a11 = fmaf(w1, x1, a11);
            }
          }
#pragma unroll 8
          for (int k = 0; k < 256; ++k) {
            u32 wv = wq[(size_t)(KI + k) * 512 + tid];
            float w0 = bf2f((u16)wv), w1 = bf2f((u16)(wv >> 16));
            float h0 = h[k], h1 = h[256 + k];
            a00 = fmaf(w0, h0, a00); a01 = fmaf(w0, h1, a01);
            a10 = fmaf(w1, h0, a10); a11 = fmaf(w1, h1, a11);
          }
          *(float2*)&graw[2 * tid]        = make_float2(a00, a10);
          *(float2*)&graw[1024 + 2 * tid] = make_float2(a01, a11);
          __syncthreads();

          // pointwise: thread -> (bb, unit j)
          {
            int bb = tid >> 8, j = tid & 255;
            float iv = sigm(graw[bb * 1024 + j] + bia[j]);
            float fv = sigm(graw[bb * 1024 + 256 + j] + bia[256 + j]);
            float gv = tanhf(graw[bb * 1024 + 512 + j] + bia[512 + j]);
            float ov = sigm(graw[bb * 1024 + 768 + j] + bia[768 + j]);
            float c1 = fv * c[bb * 256 + j] + iv * gv;
            c[bb * 256 + j] = c1;
            float h1 = ov * tanhf(c1);
            h[bb * 256 + j] = h1;
            if (layer == 0)
              ((u16*)(ws + H1B_))[((size_t)tt * 64 + b0 + bb) * 512 + d * 256 + j] = f2bf(h1);
            else
              ((u16*)(ws + ENCQ_))[((size_t)(b0 + bb) * 512 + d * 256 + j) * 512 + tt] = f2bf(h1);
          }
          __syncthreads();
        }
        if (layer == 1) {  // publish final h/c for decoder init
          int bb = tid >> 8, j = tid & 255;
          ws[HF_ + (size_t)(d * 256 + j) * 64 + b0 + bb] = h[bb * 256 + j];
          ws[CF_ + (size_t)(d * 256 + j) * 64 + b0 + bb] = c[bb * 256 + j];
        }
      }
      fullbar(bar, wg);   // L0->L1: H1B visible; L1->dec: ENCQ/HF/CF visible
    }
  }

  // ---------- decoder: 32 clusters x 8 WGs, 2 batches each; K-split gate GEMM ----------
  const int cl = wg >> 3, sl = wg & 7;
  const int b0 = 2 * cl;
  unsigned* mb = bar + 4096 + cl * 64;

  u32* slab = (u32*)smem;
  float* wsmf = smem + WSM_F;
  float* actL = smem + ACTL_F;
  float* red = smem + RED_F;
  float* gts = smem + GTS_F;
  float* bi  = smem + BI_F;
  float* hcl = smem + HCL_F;
  float* cxl = smem + CXL_F;
  float* wps = smem + WPS_F;
  float* smx = smem + SMX_F;

  for (int bb = 0; bb < 2; ++bb) {
    const u32* src = (const u32*)((const u16*)(ws + ENCQ_)) + ((size_t)(b0 + bb) * 512 + sl * 64) * 256;
    for (int i = tid; i < 16384; i += NT) {
      int u = i >> 8, c = i & 255;
      slab[(bb * 64 + u) * 256 + (c ^ (u & 31))] = src[i];
    }
  }
  if (tid < 256) {
    int row = (tid >> 6) * 512 + sl * 64 + (tid & 63);
    bi[tid] = bihd[row] + bhhd[row];
  }
  if (tid < 64) wps[tid] = Wp[sl * 64 + tid];
  if (tid < 128) {
    int bb = tid >> 6, u = tid & 63;
    hcl[bb * 64 + u]       = ald(ws + HF_ + (size_t)(sl * 64 + u) * 64 + (b0 + bb));
    hcl[128 + bb * 64 + u] = ald(ws + CF_ + (size_t)(sl * 64 + u) * 64 + (b0 + bb));
  }
  __syncthreads();
  const float bp0 = bp[0];

  for (int t = 0; t < 512; ++t) {
    // ===== A: scores for my 64-unit slice, both batches (local h,c) =====
    {
      int c = tid >> 1, sh = (tid & 1) * 16;
      float a00 = 0.f, a01 = 0.f, a10 = 0.f, a11 = 0.f;
#pragma unroll 8
      for (int u = 0; u < 64; ++u) {
        int sw = c ^ (u & 31);
        u32 e0 = slab[u * 256 + sw];
        u32 e1 = slab[(64 + u) * 256 + sw];
        float f0 = bf2f((u16)(e0 >> sh));
        float f1 = bf2f((u16)(e1 >> sh));
        a00 = fmaf(f0, hcl[u], a00);        a01 = fmaf(f0, hcl[128 + u], a01);
        a10 = fmaf(f1, hcl[64 + u], a10);   a11 = fmaf(f1, hcl[192 + u], a11);
      }
      size_t base = SCP_ + (((size_t)cl * 2) * 2 * 8 + sl) * 512 + tid;
      ast(ws + base,            a00);
      ast(ws + base + 8 * 512,  a01);
      ast(ws + base + 16 * 512, a10);
      ast(ws + base + 24 * 512, a11);
    }
    mbar8(mb);

    if (sl == 0 && tid >= 510 && t > 0) {
      int bb = tid - 510;
      float v = bp0;
#pragma unroll
      for (int s8 = 0; s8 < 8; ++s8)
        v += ald(ws + PROJ_ + ((size_t)(t & 1) * 64 + b0 + bb) * 8 + s8);
      out[(size_t)(b0 + bb) * 512 + (t - 1)] = v;
    }

    // ===== B1: reduce score slices + softmax (replicated, f32 LDS) =====
    {
      int bb = tid >> 8, i2 = tid & 255;
      float v00 = 0.f, v01 = 0.f, v10 = 0.f, v11 = 0.f;
      const float* base = ws + SCP_ + (((size_t)cl * 2 + bb) * 2) * 8 * 512;
#pragma unroll
      for (int s8 = 0; s8 < 8; ++s8) {
        v00 += ald(base + (size_t)s8 * 512 + 2 * i2);
        v01 += ald(base + (size_t)s8 * 512 + 2 * i2 + 1);
        v10 += ald(base + (size_t)(8 + s8) * 512 + 2 * i2);
        v11 += ald(base + (size_t)(8 + s8) * 512 + 2 * i2 + 1);
      }
      float m0 = fmaxf(v00, v01), m1 = fmaxf(v10, v11);
#pragma unroll
      for (int o = 1; o <= 32; o <<= 1) { m0 = fmaxf(m0, __shfl_xor(m0, o)); m1 = fmaxf(m1, __shfl_xor(m1, o)); }
      if (lane == 0) { smx[q] = m0; smx[8 + q] = m1; }
      __syncthreads();
      m0 = smx[bb * 4]; m1 = smx[8 + bb * 4];
#pragma unroll
      for (int wv = 1; wv < 4; ++wv) { m0 = fmaxf(m0, smx[bb * 4 + wv]); m1 = fmaxf(m1, smx[8 + bb * 4 + wv]); }
      float e00 = expf(v00 - m0), e01 = expf(v01 - m0);
      float e10 = expf(v10 - m1), e11 = expf(v11 - m1);
      float z0 = e00 + e01, z1 = e10 + e11;
#pragma unroll
      for (int o = 1; o <= 32; o <<= 1) { z0 += __shfl_xor(z0, o); z1 += __shfl_xor(z1, o); }
      if (lane == 0) { smx[16 + q] = z0; smx[24 + q] = z1; }
      __syncthreads();
      z0 = 0.f; z1 = 0.f;
#pragma unroll
      for (int wv = 0; wv < 4; ++wv) { z0 += smx[16 + bb * 4 + wv]; z1 += smx[24 + bb * 4 + wv]; }
      wsmf[(bb * 2 + 0) * 512 + 2 * i2]     = e00 / z0;
      wsmf[(bb * 2 + 0) * 512 + 2 * i2 + 1] = e01 / z0;
      wsmf[(bb * 2 + 1) * 512 + 2 * i2]     = e10 / z1;
      wsmf[(bb * 2 + 1) * 512 + 2 * i2 + 1] = e11 / z1;
    }
    __syncthreads();

    // ===== B2: ctx for my slice over all s (local) =====
    {
      int bb = q >> 2, oct = q & 3, u = lane;
      float ch = 0.f, cc = 0.f;
#pragma unroll 8
      for (int i = 0; i < 64; ++i) {
        int c = oct * 64 + i;
        u32 e = slab[(bb * 64 + u) * 256 + (c ^ (u & 31))];
        float e0 = bf2f((u16)e), e1 = bf2f((u16)(e >> 16));
        int s = 2 * c;
        ch += e0 * wsmf[(bb * 2 + 0) * 512 + s] + e1 * wsmf[(bb * 2 + 0) * 512 + s + 1];
        cc += e0 * wsmf[(bb * 2 + 1) * 512 + s] + e1 * wsmf[(bb * 2 + 1) * 512 + s + 1];
      }
      red[((bb * 64 + u) * 2 + 0) * 4 + oct] = ch;
      red[((bb * 64 + u) * 2 + 1) * 4 + oct] = cc;
    }
    __syncthreads();
    if (tid < 256) {
      int bb = tid >> 7, u = (tid >> 1) & 63, hc = tid & 1;
      float v = red[((bb * 64 + u) * 2 + hc) * 4 + 0] + red[((bb * 64 + u) * 2 + hc) * 4 + 1]
              + red[((bb * 64 + u) * 2 + hc) * 4 + 2] + red[((bb * 64 + u) * 2 + hc) * 4 + 3];
      cxl[(bb * 2 + hc) * 64 + u] = v;
    }
    __syncthreads();

    // ===== B3: stage local act chunk [x_sl | ctxh_sl | ctxc_sl | h_sl] =====
    if (tid < 400) {
      int bb = (tid >= 200), k = tid - bb * 200;
      float v;
      if (k < 8)        v = bf2f(((const u16*)(ws + XB_))[((size_t)t * 64 + (b0 + bb)) * 64 + sl * 8 + k]);
      else if (k < 72)  v = cxl[(bb * 2 + 0) * 64 + (k - 8)];
      else if (k < 136) v = cxl[(bb * 2 + 1) * 64 + (k - 72)];
      else              v = hcl[bb * 64 + (k - 136)];
      actL[bb * 200 + k] = v;
    }
    __syncthreads();

    // ===== B4: K-split gate GEMM: all 2048 rows x my 200-K chunk x 2 batches =====
    {
      const u64* wq = (const u64*)(ws + WDK_) + (size_t)sl * 200 * 512;
      float a[4][2] = {{0.f,0.f},{0.f,0.f},{0.f,0.f},{0.f,0.f}};
#pragma unroll 8
      for (int k = 0; k < 200; ++k) {
        u64 wv = wq[(size_t)k * 512 + tid];
        float A0 = actL[k], A1 = actL[200 + k];
        float w0 = bf2f((u16)wv), w1 = bf2f((u16)(wv >> 16));
        float w2 = bf2f((u16)(wv >> 32)), w3 = bf2f((u16)(wv >> 48));
        a[0][0] = fmaf(w0, A0, a[0][0]); a[0][1] = fmaf(w0, A1, a[0][1]);
        a[1][0] = fmaf(w1, A0, a[1][0]); a[1][1] = fmaf(w1, A1, a[1][1]);
        a[2][0] = fmaf(w2, A0, a[2][0]); a[2][1] = fmaf(w2, A1, a[2][1]);
        a[3][0] = fmaf(w3, A0, a[3][0]); a[3][1] = fmaf(w3, A1, a[3][1]);
      }
      u64* gp = (u64*)(ws + GP_) + ((size_t)cl * 8 + sl) * 2048;
#pragma unroll
      for (int r = 0; r < 4; ++r)
        a64st(gp + 4 * tid + r, pk2f(a[r][0], a[r][1]));
    }
    mbar8(mb);

    // ===== C: reduce 8 gate partials for my 256 rows; pointwise; PROJ =====
    if (tid < 256) {
      int gr = (tid >> 6) * 512 + sl * 64 + (tid & 63);
      const u64* gpb = (const u64*)(ws + GP_) + (size_t)cl * 8 * 2048;
      float a0 = bi[tid], a1 = bi[tid];
#pragma unroll
      for (int s8 = 0; s8 < 8; ++s8) {
        u64 v = a64ld(gpb + (size_t)s8 * 2048 + gr);
        a0 += __uint_as_float((u32)v);
        a1 += __uint_as_float((u32)(v >> 32));
      }
      gts[tid] = a0; gts[256 + tid] = a1;
    }
    __syncthreads();
    if (tid < 128) {
      int bb = tid >> 6, u = tid & 63;
      float iv = sigm(gts[bb * 256 + u]);
      float fv = sigm(gts[bb * 256 + 64 + u]);
      float gv = tanhf(gts[bb * 256 + 128 + u]);
      float ov = sigm(gts[bb * 256 + 192 + u]);
      float c1 = fv * hcl[128 + bb * 64 + u] + iv * gv;
      hcl[128 + bb * 64 + u] = c1;
      float h1 = ov * tanhf(c1);
      hcl[bb * 64 + u] = h1;
      float pv = h1 * wps[u];
#pragma unroll
      for (int o = 1; o <= 32; o <<= 1) pv += __shfl_xor(pv, o);
      if (u == 0)
        ast(ws + PROJ_ + ((size_t)((t + 1) & 1) * 64 + b0 + bb) * 8 + sl, pv);
    }
    __syncthreads();
  }

  // ---------- epilogue ----------
  mbar8(mb);
  if (sl == 0 && tid < 2) {
    int bb = tid;
    float v = bp0;
#pragma unroll
    for (int s8 = 0; s8 < 8; ++s8)
      v += ald(ws + PROJ_ + ((size_t)0 * 64 + b0 + bb) * 8 + s8);
    out[(size_t)(b0 + bb) * 512 + 511] = v;
  }
}

extern "C" void kernel_launch(void* const* d_in, const int* in_sizes, int n_in,
                              void* d_out, int out_size, void* d_ws, size_t ws_size,
                              hipStream_t stream) {
  const float* x    = (const float*)d_in[0];
  const float* Wih0 = (const float*)d_in[1];
  const float* Whh0 = (const float*)d_in[2];
  const float* bih0 = (const float*)d_in[3];
  const float* bhh0 = (const float*)d_in[4];
  const float* Wih1 = (const float*)d_in[5];
  const float* Whh1 = (const float*)d_in[6];
  const float* bih1 = (const float*)d_in[7];
  const float* bhh1 = (const float*)d_in[8];
  const float* Wihd = (const float*)d_in[9];
  const float* Whhd = (const float*)d_in[10];
  const float* bihd = (const float*)d_in[11];
  const float* bhhd = (const float*)d_in[12];
  const float* Wp   = (const float*)d_in[13];
  const float* bp   = (const float*)d_in[14];
  float* out = (float*)d_out;
  float* ws  = (float*)d_ws;
  (void)ws_size; (void)n_in; (void)in_sizes; (void)out_size;

  hipMemsetAsync(d_ws, 0, 32768, stream);

  hipFuncSetAttribute((const void*)seq2seq_ker,
                      hipFuncAttributeMaxDynamicSharedMemorySize, SMEM_F * 4);

  hipLaunchKernelGGL(seq2seq_ker, dim3(NWG), dim3(NT), SMEM_F * 4, stream,
                     x, Wih0, Whh0, bih0, bhh0, Wih1, Whh1, bih1, bhh1,
                     Wihd, Whhd, bihd, bhhd, Wp, bp, out, ws);
}

// Round 12
// 28992.728 us; speedup vs baseline: 1.7268x; 1.7268x over previous
//
#include <hip/hip_runtime.h>
#include <cmath>

#define NWG 256
#define NT  512

typedef unsigned long long u64;
typedef unsigned short u16;
typedef unsigned int u32;

// ---------------- workspace layout (float offsets) ----------------
static constexpr size_t XB_   = 8192;                         // u16 [512t][64b][64k]
static constexpr size_t H1B_  = XB_   + 1048576;              // u32 [512t][64b][256kp] (bf16 pairs)
static constexpr size_t ENCQ_ = H1B_  + 8388608;              // u16 [64b][512k][512s]
static constexpr size_t WQ0_  = ENCQ_ + 8388608;              // u32 [2d][320k][512p] rows 2p,2p+1
static constexpr size_t WHH1_ = WQ0_  + 327680;               // u32 [2d][256k][512p]
static constexpr size_t WI1G_ = WHH1_ + 262144;               // u64 [512k][512q] rows 4q..4q+3 (2d x 1024)
static constexpr size_t WDQ_  = WI1G_ + 524288;               // u16 [4j4][1600k][512r]
static constexpr size_t HF_   = WDQ_  + 1638400;              // f32 [512k][64b]
static constexpr size_t CF_   = HF_   + 32768;                // f32 [512k][64b]
static constexpr size_t SCP_  = CF_   + 32768;                // f32 [64b][4j4][2hc][512s]
static constexpr size_t CTXB_ = SCP_  + 262144;               // u16 [64b][1024]
static constexpr size_t HB_   = CTXB_ + 32768;                // u16 [2buf][64b][512k]
static constexpr size_t PROJ_ = HB_   + 32768;                // f32 [2buf][64b][4j4]
static constexpr size_t GX_   = PROJ_ + 512;                  // u32 [512t][64b][1024rp] (bf16 pairs)
static constexpr size_t WS_NEED_GX = (GX_ + (size_t)512*64*1024) * 4;  // bytes

// ---------------- LDS layout (float offsets) ----------------
// decoder (r5/round-6 proven 4-WG layout):
static constexpr int SLAB_F = 0;       // u32 [128u][256c] swizzled  32768
static constexpr int ACT_F  = 32768;   // f32 act[1600]
static constexpr int WH_F   = 34368;   // f32 wh[512]
static constexpr int WC_F   = 34880;   // f32 wc[512]
static constexpr int RED_F  = 35392;   // f32 [2048]
static constexpr int GT_F   = 37440;   // f32 [512]
static constexpr int BI_F   = 37952;   // f32 [512]
static constexpr int HL_F   = 38464;   // f32 h_loc[128]
static constexpr int CL_F   = 38592;   // f32 c_loc[128]
static constexpr int WPS_F  = 38720;   // f32 [128]
static constexpr int CXL_F  = 38848;   // f32 [256]
static constexpr int SMX_F  = 39104;   // f32 [64]
static constexpr int SMEM_F = 39168;   // 156,672 B
// encoder aliases (time-disjoint): h[256]@0, c[256]@256, xin[512]@512, graw[1024]@1024, bia[1024]@2048
static constexpr int EH_F = 0, EC_F = 256, EX_F = 512, EG_F = 1024, EB_F = 2048;
// G1 gemm alias: tile u32[64b][256kp] @0 (16384 fl)

__device__ __forceinline__ float sigm(float v) { return 1.f / (1.f + expf(-v)); }
__device__ __forceinline__ u16 f2bf(float f) {
  u32 u = __float_as_uint(f);
  u += 0x7fffu + ((u >> 16) & 1u);
  return (u16)(u >> 16);
}
__device__ __forceinline__ float bf2f(u16 h) { return __uint_as_float((u32)h << 16); }
__device__ __forceinline__ u32 pk2bf(float a, float b) {
  return (u32)f2bf(a) | ((u32)f2bf(b) << 16);
}
__device__ __forceinline__ u64 pk4(const float* p) {
  return (u64)f2bf(p[0]) | ((u64)f2bf(p[1]) << 16) | ((u64)f2bf(p[2]) << 32) | ((u64)f2bf(p[3]) << 48);
}

__device__ __forceinline__ unsigned uld(unsigned* p) {
  return __hip_atomic_load(p, __ATOMIC_RELAXED, __HIP_MEMORY_SCOPE_AGENT);
}
__device__ __forceinline__ unsigned uadd(unsigned* p) {
  return __hip_atomic_fetch_add(p, 1u, __ATOMIC_RELAXED, __HIP_MEMORY_SCOPE_AGENT);
}
__device__ __forceinline__ float ald(const float* p) {
  return __hip_atomic_load(p, __ATOMIC_RELAXED, __HIP_MEMORY_SCOPE_AGENT);
}
__device__ __forceinline__ void ast(float* p, float v) {
  __hip_atomic_store(p, v, __ATOMIC_RELAXED, __HIP_MEMORY_SCOPE_AGENT);
}
__device__ __forceinline__ u64 a64ld(const u64* p) {
  return __hip_atomic_load(p, __ATOMIC_RELAXED, __HIP_MEMORY_SCOPE_AGENT);
}
__device__ __forceinline__ void a64st(u64* p, u64 v) {
  __hip_atomic_store(p, v, __ATOMIC_RELAXED, __HIP_MEMORY_SCOPE_AGENT);
}
__device__ __forceinline__ void acqf() { __builtin_amdgcn_fence(__ATOMIC_ACQUIRE, "agent"); }
__device__ __forceinline__ void relf() { __builtin_amdgcn_fence(__ATOMIC_RELEASE, "agent"); }

// full-grid barrier WITH fences (phase boundaries only)
__device__ __forceinline__ void fullbar(unsigned* bar, int wg) {
  __syncthreads();
  if (threadIdx.x == 0) {
    relf();
    unsigned g = uld(bar);
    if (((uadd(&bar[32 + (wg >> 3) * 32]) + 1) & 7) == 0)
      if (((uadd(&bar[1056 + (wg >> 6) * 32]) + 1) & 7) == 0)
        if (((uadd(&bar[1184]) + 1) & 3) == 0)
          uadd(bar);
    while (uld(bar) == g) __builtin_amdgcn_s_sleep(4);
    acqf();
  }
  __syncthreads();
}

// 4-WG relaxed minibar, fence-free
__device__ __forceinline__ void mbar4(unsigned* base) {
  __syncthreads();
  if (threadIdx.x == 0) {
    unsigned g = uld(base);
    if (((uadd(&base[32]) + 1) & 3) == 0) uadd(base);
    while (uld(base) == g) __builtin_amdgcn_s_sleep(1);
  }
  __syncthreads();
}

extern "C" __global__ void __launch_bounds__(NT, 1)
seq2seq_ker(const float* __restrict__ x,
            const float* __restrict__ Wih0, const float* __restrict__ Whh0,
            const float* __restrict__ bih0, const float* __restrict__ bhh0,
            const float* __restrict__ Wih1, const float* __restrict__ Whh1,
            const float* __restrict__ bih1, const float* __restrict__ bhh1,
            const float* __restrict__ Wihd, const float* __restrict__ Whhd,
            const float* __restrict__ bihd, const float* __restrict__ bhhd,
            const float* __restrict__ Wp,   const float* __restrict__ bp,
            float* out, float* ws, int use_gx) {
  extern __shared__ float smem[];
  unsigned* bar = (unsigned*)ws;
  const int tid = threadIdx.x;
  const int wg  = blockIdx.x;
  const int gtid = wg * NT + tid;
  const int lane = tid & 63, q = tid >> 6;

  // ---------- prologue ----------
  for (size_t i = gtid; i < (size_t)512 * 64 * 64; i += (size_t)NWG * NT) {
    int k = (int)(i & 63), tt2 = (int)((i >> 6) & 511), bb = (int)(i >> 15);
    ((u16*)(ws + XB_))[((size_t)tt2 * 64 + bb) * 64 + k] = f2bf(x[i]);
  }
  // WQ0: [d][320k][512p], rows 2p,2p+1
  for (size_t idx = gtid; idx < (size_t)2 * 320 * 512; idx += (size_t)NWG * NT) {
    int p = (int)(idx & 511);
    int k = (int)((idx >> 9) % 320);
    int d = (int)((idx >> 9) / 320);
    u32 v = 0;
#pragma unroll
    for (int j = 0; j < 2; ++j) {
      int row = 2 * p + j;
      float wv = (k < 64) ? Wih0[(size_t)d * 65536 + (size_t)row * 64 + k]
                          : Whh0[(size_t)d * 262144 + (size_t)row * 256 + (k - 64)];
      v |= (u32)f2bf(wv) << (16 * j);
    }
    ((u32*)(ws + WQ0_))[idx] = v;
  }
  // WHH1: [d][256k][512p]
  for (size_t idx = gtid; idx < (size_t)2 * 256 * 512; idx += (size_t)NWG * NT) {
    int p = (int)(idx & 511);
    int kk = (int)(idx >> 9);        // 0..511
    int k = kk & 255, d = kk >> 8;
    u32 v = (u32)f2bf(Whh1[(size_t)d * 262144 + (size_t)(2 * p) * 256 + k])
          | ((u32)f2bf(Whh1[(size_t)d * 262144 + (size_t)(2 * p + 1) * 256 + k]) << 16);
    ((u32*)(ws + WHH1_))[idx] = v;
  }
  // WI1G: u64 [512k][512q], rows 4q..4q+3 global over (2d x 1024)
  for (size_t idx = gtid; idx < (size_t)512 * 512; idx += (size_t)NWG * NT) {
    int q4 = (int)(idx & 511);
    int k  = (int)(idx >> 9);
    u64 v = 0;
#pragma unroll
    for (int j = 0; j < 4; ++j) {
      int row = 4 * q4 + j;
      int dd = row >> 10, loc = row & 1023;
      v |= (u64)f2bf(Wih1[(size_t)dd * 524288 + (size_t)loc * 512 + k]) << (16 * j);
    }
    ((u64*)(ws + WI1G_))[idx] = v;
  }
  // WDQ (decoder, 4-WG layout): [j4][1600k][128p u64], 4 rows per p
  for (size_t idx = gtid; idx < (size_t)4 * 1600 * 128; idx += (size_t)NWG * NT) {
    int p = (int)(idx & 127);
    int k = (int)((idx >> 7) % 1600);
    int jq = (int)((idx >> 7) / 1600);
    u64 v = 0;
#pragma unroll
    for (int j = 0; j < 4; ++j) {
      int r = 4 * p + j;
      int row = (r >> 7) * 512 + jq * 128 + (r & 127);
      float wv = (k < 1088) ? Wihd[(size_t)row * 1088 + k]
                            : Whhd[(size_t)row * 512 + (k - 1088)];
      v |= (u64)f2bf(wv) << (16 * j);
    }
    ((u64*)((u16*)(ws + WDQ_)))[idx] = v;
  }
  fullbar(bar, wg);   // (1) XB / weights visible

  // ---------- encoder layer 0: 128 WGs, batch-local, zero inter-WG sync ----------
  {
    float* h = smem + EH_F;
    float* c = smem + EC_F;
    float* xin = smem + EX_F;
    float* graw = smem + EG_F;
    float* bia = smem + EB_F;
    const int d = wg >> 6, b = wg & 63;
    if (wg < 128) {
      for (int i = tid; i < 1024; i += NT) bia[i] = bih0[d * 1024 + i] + bhh0[d * 1024 + i];
      if (tid < 256) { h[tid] = 0.f; c[tid] = 0.f; }
      __syncthreads();
      const u32* wq0 = (const u32*)(ws + WQ0_) + (size_t)d * 320 * 512;
      for (int t = 0; t < 512; ++t) {
        const int tt = d ? (511 - t) : t;
        if (tid < 64) xin[tid] = bf2f(((const u16*)(ws + XB_))[((size_t)tt * 64 + b) * 64 + tid]);
        __syncthreads();
        float a0 = 0.f, a1 = 0.f;
#pragma unroll 8
        for (int k = 0; k < 64; ++k) {
          u32 wv = wq0[(size_t)k * 512 + tid];
          float xv = xin[k];
          a0 = fmaf(bf2f((u16)wv), xv, a0);
          a1 = fmaf(bf2f((u16)(wv >> 16)), xv, a1);
        }
#pragma unroll 8
        for (int k = 0; k < 256; ++k) {
          u32 wv = wq0[(size_t)(64 + k) * 512 + tid];
          float hv = h[k];
          a0 = fmaf(bf2f((u16)wv), hv, a0);
          a1 = fmaf(bf2f((u16)(wv >> 16)), hv, a1);
        }
        *(float2*)&graw[2 * tid] = make_float2(a0, a1);
        __syncthreads();
        if (tid < 256) {
          float iv = sigm(graw[tid] + bia[tid]);
          float fv = sigm(graw[256 + tid] + bia[256 + tid]);
          float gv = tanhf(graw[512 + tid] + bia[512 + tid]);
          float ov = sigm(graw[768 + tid] + bia[768 + tid]);
          float c1 = fv * c[tid] + iv * gv;
          c[tid] = c1;
          h[tid] = ov * tanhf(c1);
        }
        __syncthreads();
        if (tid < 128)
          ((u32*)(ws + H1B_))[((size_t)tt * 64 + b) * 256 + d * 128 + tid] = pk2bf(h[2 * tid], h[2 * tid + 1]);
      }
    }
  }
  fullbar(bar, wg);   // (2) H1B visible

  // ---------- G1: gx = Wih1 @ H1 for all t (parallel GEMM), bf16 out ----------
  if (use_gx) {
    u32* tile = (u32*)smem;   // [64b][256kp]
    for (int tp = 0; tp < 2; ++tp) {
      int t = wg * 2 + tp;
      __syncthreads();
      for (int i = tid; i < 16384; i += NT) {
        int bb = i >> 8, kp = i & 255;
        tile[i] = ((const u32*)(ws + H1B_))[((size_t)t * 64 + bb) * 256 + kp];
      }
      __syncthreads();
      const u64* wi = (const u64*)(ws + WI1G_);
      for (int bt = 0; bt < 8; ++bt) {
        float acc[4][8];
#pragma unroll
        for (int j = 0; j < 4; ++j)
#pragma unroll
          for (int b2 = 0; b2 < 8; ++b2) acc[j][b2] = 0.f;
#pragma unroll 2
        for (int k2 = 0; k2 < 256; ++k2) {
          u64 we = wi[(size_t)(2 * k2) * 512 + tid];
          u64 wo = wi[(size_t)(2 * k2 + 1) * 512 + tid];
          float w0e = bf2f((u16)we), w1e = bf2f((u16)(we >> 16));
          float w2e = bf2f((u16)(we >> 32)), w3e = bf2f((u16)(we >> 48));
          float w0o = bf2f((u16)wo), w1o = bf2f((u16)(wo >> 16));
          float w2o = bf2f((u16)(wo >> 32)), w3o = bf2f((u16)(wo >> 48));
#pragma unroll
          for (int b2 = 0; b2 < 8; ++b2) {
            u32 tv = tile[(bt * 8 + b2) * 256 + k2];
            float ae = bf2f((u16)tv), ao = bf2f((u16)(tv >> 16));
            acc[0][b2] = fmaf(w0e, ae, fmaf(w0o, ao, acc[0][b2]));
            acc[1][b2] = fmaf(w1e, ae, fmaf(w1o, ao, acc[1][b2]));
            acc[2][b2] = fmaf(w2e, ae, fmaf(w2o, ao, acc[2][b2]));
            acc[3][b2] = fmaf(w3e, ae, fmaf(w3o, ao, acc[3][b2]));
          }
        }
#pragma unroll
        for (int b2 = 0; b2 < 8; ++b2) {
          int b = bt * 8 + b2;
          u32* gxp = (u32*)(ws + GX_) + ((size_t)t * 64 + b) * 1024;
          gxp[2 * tid]     = pk2bf(acc[0][b2], acc[1][b2]);
          gxp[2 * tid + 1] = pk2bf(acc[2][b2], acc[3][b2]);
        }
      }
    }
  }
  fullbar(bar, wg);   // (3) GX visible (no-op content if !use_gx)

  // ---------- encoder layer 1: 128 WGs, batch-local; K=256 recurrent (+gx) ----------
  {
    float* h = smem + EH_F;
    float* c = smem + EC_F;
    float* xin = smem + EX_F;
    float* graw = smem + EG_F;
    float* bia = smem + EB_F;
    const int d = wg >> 6, b = wg & 63;
    if (wg < 128) {
      for (int i = tid; i < 1024; i += NT) bia[i] = bih1[d * 1024 + i] + bhh1[d * 1024 + i];
      if (tid < 256) { h[tid] = 0.f; c[tid] = 0.f; }
      __syncthreads();
      const u32* whh = (const u32*)(ws + WHH1_) + (size_t)d * 256 * 512;
      const u64* wi = (const u64*)(ws + WI1G_);
      for (int t = 0; t < 512; ++t) {
        const int tt = d ? (511 - t) : t;
        if (!use_gx) {
          if (tid < 256) {
            u32 v = ((const u32*)(ws + H1B_))[((size_t)tt * 64 + b) * 256 + tid];
            xin[2 * tid] = bf2f((u16)v);
            xin[2 * tid + 1] = bf2f((u16)(v >> 16));
          }
        }
        __syncthreads();
        float a0, a1;
        if (use_gx) {
          u32 g = ((const u32*)(ws + GX_))[((size_t)tt * 64 + b) * 1024 + d * 512 + tid];
          a0 = bf2f((u16)g);
          a1 = bf2f((u16)(g >> 16));
        } else {
          a0 = 0.f; a1 = 0.f;
          int half = tid & 1;
#pragma unroll 8
          for (int k = 0; k < 512; ++k) {
            u64 wv = wi[(size_t)k * 512 + ((d * 512 + tid) >> 1)];
            u32 hv = (u32)(wv >> (32 * half));
            float xv = xin[k];
            a0 = fmaf(bf2f((u16)hv), xv, a0);
            a1 = fmaf(bf2f((u16)(hv >> 16)), xv, a1);
          }
        }
#pragma unroll 8
        for (int k = 0; k < 256; ++k) {
          u32 wv = whh[(size_t)k * 512 + tid];
          float hv = h[k];
          a0 = fmaf(bf2f((u16)wv), hv, a0);
          a1 = fmaf(bf2f((u16)(wv >> 16)), hv, a1);
        }
        *(float2*)&graw[2 * tid] = make_float2(a0, a1);
        __syncthreads();
        if (tid < 256) {
          float iv = sigm(graw[tid] + bia[tid]);
          float fv = sigm(graw[256 + tid] + bia[256 + tid]);
          float gv = tanhf(graw[512 + tid] + bia[512 + tid]);
          float ov = sigm(graw[768 + tid] + bia[768 + tid]);
          float c1 = fv * c[tid] + iv * gv;
          c[tid] = c1;
          float h1 = ov * tanhf(c1);
          h[tid] = h1;
          ((u16*)(ws + ENCQ_))[((size_t)b * 512 + d * 256 + tid) * 512 + tt] = f2bf(h1);
        }
        __syncthreads();
      }
      if (tid < 256) {
        ws[HF_ + (size_t)(d * 256 + tid) * 64 + b] = h[tid];
        ws[CF_ + (size_t)(d * 256 + tid) * 64 + b] = c[tid];
      }
    }
  }
  fullbar(bar, wg);   // (4) ENCQ / HF / CF visible

  // ---------- decoder: 64 independent 4-WG clusters (proven round-6 structure) ----------
  const int b  = wg >> 2;
  const int j4 = wg & 3;
  unsigned* mb = bar + 4096 + b * 64;

  u32* slab = (u32*)smem;
  float* act = smem + ACT_F;
  float* wh  = smem + WH_F;
  float* wc  = smem + WC_F;
  float* red = smem + RED_F;
  float* gt  = smem + GT_F;
  float* bi  = smem + BI_F;
  float* h_loc = smem + HL_F;
  float* c_loc = smem + CL_F;
  float* wps = smem + WPS_F;
  float* cxl = smem + CXL_F;
  float* smx = smem + SMX_F;

  {
    const u32* src = (const u32*)((const u16*)(ws + ENCQ_)) + ((size_t)b * 512 + j4 * 128) * 256;
    for (int i = tid; i < 32768; i += NT) {
      int u = i >> 8, c2 = i & 255;
      slab[u * 256 + (c2 ^ (u & 31))] = src[i];
    }
  }
  for (int r = tid; r < 512; r += NT) {
    int row = (r >> 7) * 512 + j4 * 128 + (r & 127);
    bi[r] = bihd[row] + bhhd[row];
  }
  if (tid < 128) {
    wps[tid] = Wp[j4 * 128 + tid];
    h_loc[tid] = ald(ws + HF_ + (size_t)(j4 * 128 + tid) * 64 + b);
    c_loc[tid] = ald(ws + CF_ + (size_t)(j4 * 128 + tid) * 64 + b);
  }
  __syncthreads();
  if (tid < 32) {
    u64 v = pk4(&h_loc[4 * tid]);
    a64st((u64*)((u16*)(ws + HB_) + ((size_t)0 * 64 + b) * 512 + j4 * 128) + tid, v);
  }
  const float bp0 = bp[0];

  for (int t = 0; t < 512; ++t) {
    // ===== scores for my 128-unit slice (fully local h,c) =====
    {
      int s = tid, c2 = s >> 1, sh = (s & 1) * 16;
      float ah = 0.f, ac = 0.f;
#pragma unroll 8
      for (int u = 0; u < 128; ++u) {
        u32 pv = slab[u * 256 + (c2 ^ (u & 31))];
        float e = bf2f((u16)(pv >> sh));
        ah = fmaf(e, h_loc[u], ah);
        ac = fmaf(e, c_loc[u], ac);
      }
      ast(ws + SCP_ + (((size_t)b * 4 + j4) * 2 + 0) * 512 + s, ah);
      ast(ws + SCP_ + (((size_t)b * 4 + j4) * 2 + 1) * 512 + s, ac);
    }
    mbar4(mb);

    // ===== reduce partials + replicated softmax over 512 =====
    {
      int s = tid;
      float sh = 0.f, sc = 0.f;
#pragma unroll
      for (int jj = 0; jj < 4; ++jj) {
        sh += ald(ws + SCP_ + (((size_t)b * 4 + jj) * 2 + 0) * 512 + s);
        sc += ald(ws + SCP_ + (((size_t)b * 4 + jj) * 2 + 1) * 512 + s);
      }
      float mh = sh, mc = sc;
#pragma unroll
      for (int o = 1; o <= 32; o <<= 1) { mh = fmaxf(mh, __shfl_xor(mh, o)); mc = fmaxf(mc, __shfl_xor(mc, o)); }
      if (lane == 0) { smx[q] = mh; smx[8 + q] = mc; }
      __syncthreads();
      mh = smx[0]; mc = smx[8];
#pragma unroll
      for (int ww = 1; ww < 8; ++ww) { mh = fmaxf(mh, smx[ww]); mc = fmaxf(mc, smx[8 + ww]); }
      float eh = expf(sh - mh), ec = expf(sc - mc);
      float zh = eh, zc = ec;
#pragma unroll
      for (int o = 1; o <= 32; o <<= 1) { zh += __shfl_xor(zh, o); zc += __shfl_xor(zc, o); }
      if (lane == 0) { smx[16 + q] = zh; smx[24 + q] = zc; }
      __syncthreads();
      zh = 0.f; zc = 0.f;
#pragma unroll
      for (int ww = 0; ww < 8; ++ww) { zh += smx[16 + ww]; zc += smx[24 + ww]; }
      wh[s] = eh / zh;
      wc[s] = ec / zc;
    }
    __syncthreads();

    // ===== ctx for my k-slice over all s (local) =====
    {
      int u = tid & 127, sq = tid >> 7, kx = u & 31;
      float ch = 0.f, cc = 0.f;
#pragma unroll 8
      for (int i = 0; i < 64; ++i) {
        int c2 = sq * 64 + i;
        u32 pv = slab[u * 256 + (c2 ^ kx)];
        float e0 = bf2f((u16)pv), e1 = bf2f((u16)(pv >> 16));
        int s = 2 * c2;
        ch += e0 * wh[s] + e1 * wh[s + 1];
        cc += e0 * wc[s] + e1 * wc[s + 1];
      }
      red[tid * 2] = ch;
      red[tid * 2 + 1] = cc;
    }
    __syncthreads();
    if (tid < 256) {
      int u = tid >> 1, hc = tid & 1;
      float v = red[(0 * 128 + u) * 2 + hc] + red[(1 * 128 + u) * 2 + hc]
              + red[(2 * 128 + u) * 2 + hc] + red[(3 * 128 + u) * 2 + hc];
      cxl[hc * 128 + u] = v;
    }
    __syncthreads();
    if (tid < 64) {  // publish ctx slice (bf16 packed) — full 128-unit coverage
      int i = tid & 31, hc = tid >> 5;
      u64 v = pk4(&cxl[hc * 128 + 4 * i]);
      a64st((u64*)((u16*)(ws + CTXB_) + (size_t)b * 1024 + hc * 512 + j4 * 128) + i, v);
    }
    mbar4(mb);

    // ===== stage act = [XB(t) | CTXB | HB(buf t&1)] ; out projection =====
    if (tid < 400) {
      u64 v;
      if (tid < 16)
        v = a64ld((const u64*)((const u16*)(ws + XB_) + ((size_t)t * 64 + b) * 64) + tid);
      else if (tid < 272)
        v = a64ld((const u64*)((const u16*)(ws + CTXB_) + (size_t)b * 1024) + (tid - 16));
      else
        v = a64ld((const u64*)((const u16*)(ws + HB_) + ((size_t)(t & 1) * 64 + b) * 512) + (tid - 272));
      float4 f = make_float4(bf2f((u16)v), bf2f((u16)(v >> 16)),
                             bf2f((u16)(v >> 32)), bf2f((u16)(v >> 48)));
      *(float4*)&act[4 * tid] = f;
    }
    if (j4 == 0 && tid == 448 && t > 0) {
      float v = bp0;
#pragma unroll
      for (int jj = 0; jj < 4; ++jj) v += ald(ws + PROJ_ + ((size_t)(t & 1) * 64 + b) * 4 + jj);
      out[(size_t)b * 512 + (t - 1)] = v;
    }
    __syncthreads();

    // ===== gate GEMM: 512 rows x K=1600, weights streamed from L2 (bf16) =====
    {
      int kq = tid >> 7, p = tid & 127;
      const u64* wq = (const u64*)((const u16*)(ws + WDQ_) + (size_t)j4 * 1600 * 512);
      float a0 = 0.f, a1 = 0.f, a2 = 0.f, a3 = 0.f;
      int k0 = kq * 400;
#pragma unroll 16
      for (int i = 0; i < 400; ++i) {
        int k = k0 + i;
        u64 wv = wq[(size_t)k * 128 + p];
        float a = act[k];
        a0 = fmaf(bf2f((u16)wv), a, a0);
        a1 = fmaf(bf2f((u16)(wv >> 16)), a, a1);
        a2 = fmaf(bf2f((u16)(wv >> 32)), a, a2);
        a3 = fmaf(bf2f((u16)(wv >> 48)), a, a3);
      }
      *(float4*)&red[tid * 4] = make_float4(a0, a1, a2, a3);
    }
    __syncthreads();
    {
      float g = bi[tid];
#pragma unroll
      for (int kq2 = 0; kq2 < 4; ++kq2) g += red[kq2 * 512 + tid];
      gt[tid] = g;
    }
    __syncthreads();
    if (tid < 128) {
      float iv = sigm(gt[tid]), fv = sigm(gt[128 + tid]);
      float gv = tanhf(gt[256 + tid]), ov = sigm(gt[384 + tid]);
      float c1 = fv * c_loc[tid] + iv * gv;
      c_loc[tid] = c1;
      h_loc[tid] = ov * tanhf(c1);
    }
    __syncthreads();
    if (tid < 32) {
      u64 v = pk4(&h_loc[4 * tid]);
      a64st((u64*)((u16*)(ws + HB_) + ((size_t)((t + 1) & 1) * 64 + b) * 512 + j4 * 128) + tid, v);
    }
    if (tid < 128) {
      float pv = h_loc[tid] * wps[tid];
#pragma unroll
      for (int o = 1; o <= 32; o <<= 1) pv += __shfl_xor(pv, o);
      if (lane == 0) smx[40 + (tid >> 6)] = pv;
    }
    __syncthreads();
    if (tid == 0)
      ast(ws + PROJ_ + ((size_t)((t + 1) & 1) * 64 + b) * 4 + j4, smx[40] + smx[41]);
  }

  // ---------- epilogue: out[b][511] ----------
  mbar4(mb);
  if (j4 == 0 && tid == 0) {
    float v = bp0;
#pragma unroll
    for (int jj = 0; jj < 4; ++jj) v += ald(ws + PROJ_ + ((size_t)0 * 64 + b) * 4 + jj);
    out[(size_t)b * 512 + 511] = v;
  }
}

extern "C" void kernel_launch(void* const* d_in, const int* in_sizes, int n_in,
                              void* d_out, int out_size, void* d_ws, size_t ws_size,
                              hipStream_t stream) {
  const float* x    = (const float*)d_in[0];
  const float* Wih0 = (const float*)d_in[1];
  const float* Whh0 = (const float*)d_in[2];
  const float* bih0 = (const float*)d_in[3];
  const float* bhh0 = (const float*)d_in[4];
  const float* Wih1 = (const float*)d_in[5];
  const float* Whh1 = (const float*)d_in[6];
  const float* bih1 = (const float*)d_in[7];
  const float* bhh1 = (const float*)d_in[8];
  const float* Wihd = (const float*)d_in[9];
  const float* Whhd = (const float*)d_in[10];
  const float* bihd = (const float*)d_in[11];
  const float* bhhd = (const float*)d_in[12];
  const float* Wp   = (const float*)d_in[13];
  const float* bp   = (const float*)d_in[14];
  float* out = (float*)d_out;
  float* ws  = (float*)d_ws;
  (void)n_in; (void)in_sizes; (void)out_size;

  int use_gx = (ws_size >= WS_NEED_GX) ? 1 : 0;

  hipMemsetAsync(d_ws, 0, 32768, stream);

  hipFuncSetAttribute((const void*)seq2seq_ker,
                      hipFuncAttributeMaxDynamicSharedMemorySize, SMEM_F * 4);

  hipLaunchKernelGGL(seq2seq_ker, dim3(NWG), dim3(NT), SMEM_F * 4, stream,
                     x, Wih0, Whh0, bih0, bhh0, Wih1, Whh1, bih1, bhh1,
                     Wihd, Whhd, bihd, bhhd, Wp, bp, out, ws, use_gx);
}